// Round 1
// baseline (1508.379 us; speedup 1.0000x reference)
//
#include <hip/hip_runtime.h>

#define N_NODES 100000
#define N_EDGES 1600000
#define DIM 64

// ---------------------------------------------------------------------------
// Kernel 1: edge scatter.  16 threads per edge, each handles a float4 (4 dims).
// msg = relu(x[src]); agg[dst] += msg  via native fp32 global atomics.
// ---------------------------------------------------------------------------
__global__ __launch_bounds__(256) void gine_scatter(
    const float* __restrict__ x,
    const int*   __restrict__ ei,     // [2, E] int32: row 0 = src, row 1 = dst
    float*       __restrict__ agg)
{
    const int t   = blockIdx.x * blockDim.x + threadIdx.x;
    const int e   = t >> 4;          // edge id
    const int sub = t & 15;          // which float4 of the 64-dim row
    if (e >= N_EDGES) return;

    const int s = ei[e];
    const int d = ei[N_EDGES + e];

    const float4 v = reinterpret_cast<const float4*>(x + (size_t)s * DIM)[sub];
    float4 r;
    r.x = fmaxf(v.x, 0.0f);
    r.y = fmaxf(v.y, 0.0f);
    r.z = fmaxf(v.z, 0.0f);
    r.w = fmaxf(v.w, 0.0f);

    float* out = agg + (size_t)d * DIM + sub * 4;
    // unsafeAtomicAdd -> global_atomic_add_f32 (native, no CAS loop)
    unsafeAtomicAdd(out + 0, r.x);
    unsafeAtomicAdd(out + 1, r.y);
    unsafeAtomicAdd(out + 2, r.z);
    unsafeAtomicAdd(out + 3, r.w);
}

// ---------------------------------------------------------------------------
// Kernel 2: per-node MLP.  One wave (64 lanes) per node; lane = channel.
// h = x + agg;  y = relu(h@W1 + b1);  out = relu(y@W2 + b2).
// Broadcast of h / y across lanes via __shfl (wave64).
// ---------------------------------------------------------------------------
__global__ __launch_bounds__(256) void gine_mlp(
    const float* __restrict__ x,
    const float* __restrict__ agg,
    const float* __restrict__ W1,
    const float* __restrict__ b1,
    const float* __restrict__ W2,
    const float* __restrict__ b2,
    float*       __restrict__ out)
{
    const int wave = (blockIdx.x * blockDim.x + threadIdx.x) >> 6;
    const int lane = threadIdx.x & 63;
    if (wave >= N_NODES) return;

    const size_t base = (size_t)wave * DIM + lane;
    const float h = x[base] + agg[base];

    // layer 1: acc_j = b1[j] + sum_i h_i * W1[i][j]   (lane = j)
    float acc = b1[lane];
    #pragma unroll
    for (int i = 0; i < DIM; ++i) {
        const float hi = __shfl(h, i, 64);
        acc = fmaf(hi, W1[i * DIM + lane], acc);
    }
    const float y = fmaxf(acc, 0.0f);

    // layer 2
    float acc2 = b2[lane];
    #pragma unroll
    for (int i = 0; i < DIM; ++i) {
        const float yi = __shfl(y, i, 64);
        acc2 = fmaf(yi, W2[i * DIM + lane], acc2);
    }
    out[base] = fmaxf(acc2, 0.0f);
}

// ---------------------------------------------------------------------------
extern "C" void kernel_launch(void* const* d_in, const int* in_sizes, int n_in,
                              void* d_out, int out_size, void* d_ws, size_t ws_size,
                              hipStream_t stream) {
    const float* x  = (const float*)d_in[0];
    const int*   ei = (const int*)d_in[1];     // [2, N_EDGES]
    const float* W1 = (const float*)d_in[2];
    const float* b1 = (const float*)d_in[3];
    const float* W2 = (const float*)d_in[4];
    const float* b2 = (const float*)d_in[5];
    float* out = (float*)d_out;

    float* agg = (float*)d_ws;                 // N_NODES * DIM floats

    // zero the aggregation buffer (harness poisons ws with 0xAA)
    hipMemsetAsync(agg, 0, (size_t)N_NODES * DIM * sizeof(float), stream);

    // scatter: 16 threads per edge
    {
        const long long total = (long long)N_EDGES * 16;
        const int block = 256;
        const int grid = (int)((total + block - 1) / block);
        gine_scatter<<<grid, block, 0, stream>>>(x, ei, agg);
    }

    // MLP: 1 wave per node, 4 nodes per 256-thread block
    {
        const int nodes_per_block = 256 / 64;
        const int grid = (N_NODES + nodes_per_block - 1) / nodes_per_block;
        gine_mlp<<<grid, 256, 0, stream>>>(x, agg, W1, b1, W2, b2, out);
    }
}

// Round 2
// 384.408 us; speedup vs baseline: 3.9239x; 3.9239x over previous
//
#include <hip/hip_runtime.h>

#define N_NODES 100000
#define N_EDGES 1600000
#define DIM 64

#define SCAN_B 256
#define NB ((N_NODES + SCAN_B - 1) / SCAN_B)   // 391 blocks

// ---------------------------------------------------------------------------
// Kernel A: degree histogram over dst (int atomics on 400 KB, L2-resident)
// ---------------------------------------------------------------------------
__global__ __launch_bounds__(256) void degree_hist(
    const int* __restrict__ ei, int* __restrict__ deg)
{
    const int e = blockIdx.x * blockDim.x + threadIdx.x;
    if (e >= N_EDGES) return;
    atomicAdd(&deg[ei[N_EDGES + e]], 1);
}

// ---------------------------------------------------------------------------
// Scan step 1: per-block exclusive scan of deg -> off, block totals -> bsum
// ---------------------------------------------------------------------------
__global__ __launch_bounds__(SCAN_B) void scan_block(
    const int* __restrict__ deg, int* __restrict__ off, int* __restrict__ bsum)
{
    __shared__ int s[SCAN_B];
    const int t = threadIdx.x;
    const int i = blockIdx.x * SCAN_B + t;
    const int v = (i < N_NODES) ? deg[i] : 0;
    s[t] = v;
    __syncthreads();
    #pragma unroll
    for (int d = 1; d < SCAN_B; d <<= 1) {
        const int add = (t >= d) ? s[t - d] : 0;
        __syncthreads();
        s[t] += add;
        __syncthreads();
    }
    if (i < N_NODES) off[i] = s[t] - v;          // exclusive
    if (t == SCAN_B - 1) bsum[blockIdx.x] = s[t]; // inclusive block total
}

// ---------------------------------------------------------------------------
// Scan step 2: exclusive scan of the 391 block totals (single block)
// ---------------------------------------------------------------------------
__global__ __launch_bounds__(512) void scan_bsum(int* __restrict__ bsum)
{
    __shared__ int s[512];
    const int t = threadIdx.x;
    const int v = (t < NB) ? bsum[t] : 0;
    s[t] = v;
    __syncthreads();
    #pragma unroll
    for (int d = 1; d < 512; d <<= 1) {
        const int add = (t >= d) ? s[t - d] : 0;
        __syncthreads();
        s[t] += add;
        __syncthreads();
    }
    if (t < NB) bsum[t] = s[t] - v;              // exclusive
}

// ---------------------------------------------------------------------------
// Scan step 3: add block offsets; write sentinel off[N] = E
// ---------------------------------------------------------------------------
__global__ __launch_bounds__(SCAN_B) void scan_add(
    int* __restrict__ off, const int* __restrict__ bsum)
{
    const int i = blockIdx.x * SCAN_B + threadIdx.x;
    if (i < N_NODES) off[i] += bsum[blockIdx.x];
    if (i == 0) off[N_NODES] = N_EDGES;
}

// ---------------------------------------------------------------------------
// Kernel C: bucket fill — slot[off[dst] + pos] = src
// ---------------------------------------------------------------------------
__global__ __launch_bounds__(256) void fill_slots(
    const int* __restrict__ ei, const int* __restrict__ off,
    int* __restrict__ cursor, int* __restrict__ slot)
{
    const int e = blockIdx.x * blockDim.x + threadIdx.x;
    if (e >= N_EDGES) return;
    const int d = ei[N_EDGES + e];
    const int pos = atomicAdd(&cursor[d], 1);
    slot[off[d] + pos] = ei[e];
}

// ---------------------------------------------------------------------------
// Kernel D: fused aggregate + MLP.  One wave per node, lane = channel.
// agg_j = sum_{s in bucket} relu(x[s][j]);  h = x[n] + agg;
// out = relu(relu(h@W1+b1)@W2 + b2)
// ---------------------------------------------------------------------------
__global__ __launch_bounds__(256) void gine_fused(
    const float* __restrict__ x,
    const int*   __restrict__ off,
    const int*   __restrict__ slot,
    const float* __restrict__ W1,
    const float* __restrict__ b1,
    const float* __restrict__ W2,
    const float* __restrict__ b2,
    float*       __restrict__ out)
{
    const int wave = (blockIdx.x * blockDim.x + threadIdx.x) >> 6;
    const int lane = threadIdx.x & 63;
    if (wave >= N_NODES) return;

    const int beg = off[wave];
    const int end = off[wave + 1];

    float agg = 0.0f;
    int k = beg;
    // 2-deep unroll for load-level parallelism
    for (; k + 2 <= end; k += 2) {
        const int s0 = slot[k];
        const int s1 = slot[k + 1];
        const float a0 = x[(size_t)s0 * DIM + lane];
        const float a1 = x[(size_t)s1 * DIM + lane];
        agg += fmaxf(a0, 0.0f) + fmaxf(a1, 0.0f);
    }
    if (k < end) {
        const int s0 = slot[k];
        agg += fmaxf(x[(size_t)s0 * DIM + lane], 0.0f);
    }

    const size_t base = (size_t)wave * DIM + lane;
    const float h = x[base] + agg;

    float acc = b1[lane];
    #pragma unroll
    for (int i = 0; i < DIM; ++i)
        acc = fmaf(__shfl(h, i, 64), W1[i * DIM + lane], acc);
    const float y = fmaxf(acc, 0.0f);

    float acc2 = b2[lane];
    #pragma unroll
    for (int i = 0; i < DIM; ++i)
        acc2 = fmaf(__shfl(y, i, 64), W2[i * DIM + lane], acc2);

    out[base] = fmaxf(acc2, 0.0f);
}

// ---------------------------------------------------------------------------
extern "C" void kernel_launch(void* const* d_in, const int* in_sizes, int n_in,
                              void* d_out, int out_size, void* d_ws, size_t ws_size,
                              hipStream_t stream) {
    const float* x  = (const float*)d_in[0];
    const int*   ei = (const int*)d_in[1];
    const float* W1 = (const float*)d_in[2];
    const float* b1 = (const float*)d_in[3];
    const float* W2 = (const float*)d_in[4];
    const float* b2 = (const float*)d_in[5];
    float* out = (float*)d_out;

    // workspace layout (ints): deg | off | cursor | bsum | slot
    int* deg    = (int*)d_ws;          // N_NODES
    int* off    = deg + 100352;        // N_NODES + 1
    int* cursor = off + 100352;        // N_NODES
    int* bsum   = cursor + 100352;     // 512
    int* slot   = bsum + 512;          // N_EDGES

    hipMemsetAsync(deg,    0, (size_t)N_NODES * sizeof(int), stream);
    hipMemsetAsync(cursor, 0, (size_t)N_NODES * sizeof(int), stream);

    const int eblocks = (N_EDGES + 255) / 256;
    degree_hist<<<eblocks, 256, 0, stream>>>(ei, deg);
    scan_block<<<NB, SCAN_B, 0, stream>>>(deg, off, bsum);
    scan_bsum<<<1, 512, 0, stream>>>(bsum);
    scan_add<<<NB, SCAN_B, 0, stream>>>(off, bsum);
    fill_slots<<<eblocks, 256, 0, stream>>>(ei, off, cursor, slot);

    const int waves_per_block = 256 / 64;
    const int grid = (N_NODES + waves_per_block - 1) / waves_per_block;
    gine_fused<<<grid, 256, 0, stream>>>(x, off, slot, W1, b1, W2, b2, out);
}

// Round 4
// 381.700 us; speedup vs baseline: 3.9517x; 1.0071x over previous
//
#include <hip/hip_runtime.h>

#define N_NODES 100000
#define N_EDGES 1600000
#define DIM 64

#define SCAN_B 256
#define NB ((N_NODES + SCAN_B - 1) / SCAN_B)   // 391 blocks

// ---------------------------------------------------------------------------
// Kernel A: degree histogram over dst (int atomics on 400 KB, L2-resident)
// ---------------------------------------------------------------------------
__global__ __launch_bounds__(256) void degree_hist(
    const int* __restrict__ ei, int* __restrict__ deg)
{
    const int e = blockIdx.x * blockDim.x + threadIdx.x;
    if (e >= N_EDGES) return;
    atomicAdd(&deg[ei[N_EDGES + e]], 1);
}

// ---------------------------------------------------------------------------
// Scan step 1: per-block exclusive scan of deg -> off, block totals -> bsum
// ---------------------------------------------------------------------------
__global__ __launch_bounds__(SCAN_B) void scan_block(
    const int* __restrict__ deg, int* __restrict__ off, int* __restrict__ bsum)
{
    __shared__ int s[SCAN_B];
    const int t = threadIdx.x;
    const int i = blockIdx.x * SCAN_B + t;
    const int v = (i < N_NODES) ? deg[i] : 0;
    s[t] = v;
    __syncthreads();
    #pragma unroll
    for (int d = 1; d < SCAN_B; d <<= 1) {
        const int add = (t >= d) ? s[t - d] : 0;
        __syncthreads();
        s[t] += add;
        __syncthreads();
    }
    if (i < N_NODES) off[i] = s[t] - v;           // exclusive
    if (t == SCAN_B - 1) bsum[blockIdx.x] = s[t]; // inclusive block total
}

// ---------------------------------------------------------------------------
// Scan step 2: exclusive scan of the 391 block totals (single block)
// ---------------------------------------------------------------------------
__global__ __launch_bounds__(512) void scan_bsum(int* __restrict__ bsum)
{
    __shared__ int s[512];
    const int t = threadIdx.x;
    const int v = (t < NB) ? bsum[t] : 0;
    s[t] = v;
    __syncthreads();
    #pragma unroll
    for (int d = 1; d < 512; d <<= 1) {
        const int add = (t >= d) ? s[t - d] : 0;
        __syncthreads();
        s[t] += add;
        __syncthreads();
    }
    if (t < NB) bsum[t] = s[t] - v;               // exclusive
}

// ---------------------------------------------------------------------------
// Scan step 3: add block offsets; write sentinel off[N] = E
// ---------------------------------------------------------------------------
__global__ __launch_bounds__(SCAN_B) void scan_add(
    int* __restrict__ off, const int* __restrict__ bsum)
{
    const int i = blockIdx.x * SCAN_B + threadIdx.x;
    if (i < N_NODES) off[i] += bsum[blockIdx.x];
    if (i == 0) off[N_NODES] = N_EDGES;
}

// ---------------------------------------------------------------------------
// Kernel C: bucket fill — slot[pos] = src, cursor pre-initialized to off[]
// ---------------------------------------------------------------------------
__global__ __launch_bounds__(256) void fill_slots(
    const int* __restrict__ ei,
    int* __restrict__ cursor, int* __restrict__ slot)
{
    const int e = blockIdx.x * blockDim.x + threadIdx.x;
    if (e >= N_EDGES) return;
    const int d = ei[N_EDGES + e];
    const int pos = atomicAdd(&cursor[d], 1);
    slot[pos] = ei[e];
}

// ---------------------------------------------------------------------------
// Kernel D: fused aggregate + MLP.  One wave per node, lane = channel.
//  - slot indices loaded coalesced (one per lane), broadcast via __shfl
//  - row gather 8-deep for load-level parallelism
// ---------------------------------------------------------------------------
__global__ __launch_bounds__(256) void gine_fused(
    const float* __restrict__ x,
    const int*   __restrict__ off,
    const int*   __restrict__ slot,
    const float* __restrict__ W1,
    const float* __restrict__ b1,
    const float* __restrict__ W2,
    const float* __restrict__ b2,
    float*       __restrict__ out)
{
    const int wave = (blockIdx.x * blockDim.x + threadIdx.x) >> 6;
    const int lane = threadIdx.x & 63;
    if (wave >= N_NODES) return;

    const int beg = off[wave];
    const int end = off[wave + 1];

    const size_t base = (size_t)wave * DIM + lane;
    const float xself = x[base];           // issue early, consumed later

    float agg = 0.0f;
    for (int kb = beg; kb < end; kb += 64) {
        const int nv = min(64, end - kb);
        // coalesced slot prefetch: lane i holds slot[kb+i]
        const int my = (kb + lane < end) ? slot[kb + lane] : 0;

        int i = 0;
        for (; i + 8 <= nv; i += 8) {
            float a[8];
            #pragma unroll
            for (int j = 0; j < 8; ++j) {
                const int s = __shfl(my, i + j, 64);
                a[j] = x[(size_t)s * DIM + lane];
            }
            #pragma unroll
            for (int j = 0; j < 8; ++j)
                agg += fmaxf(a[j], 0.0f);
        }
        for (; i < nv; ++i) {
            const int s = __shfl(my, i, 64);
            agg += fmaxf(x[(size_t)s * DIM + lane], 0.0f);
        }
    }

    const float h = xself + agg;

    float acc = b1[lane];
    #pragma unroll
    for (int i = 0; i < DIM; ++i)
        acc = fmaf(__shfl(h, i, 64), W1[i * DIM + lane], acc);
    const float y = fmaxf(acc, 0.0f);

    float acc2 = b2[lane];
    #pragma unroll
    for (int i = 0; i < DIM; ++i)
        acc2 = fmaf(__shfl(y, i, 64), W2[i * DIM + lane], acc2);

    out[base] = fmaxf(acc2, 0.0f);
}

// ---------------------------------------------------------------------------
extern "C" void kernel_launch(void* const* d_in, const int* in_sizes, int n_in,
                              void* d_out, int out_size, void* d_ws, size_t ws_size,
                              hipStream_t stream) {
    const float* x  = (const float*)d_in[0];
    const int*   ei = (const int*)d_in[1];
    const float* W1 = (const float*)d_in[2];
    const float* b1 = (const float*)d_in[3];
    const float* W2 = (const float*)d_in[4];
    const float* b2 = (const float*)d_in[5];
    float* out = (float*)d_out;

    // workspace layout (ints): deg | off | cursor | bsum | slot
    int* deg    = (int*)d_ws;          // N_NODES
    int* off    = deg + 100352;        // N_NODES + 1
    int* cursor = off + 100352;        // N_NODES
    int* bsum   = cursor + 100352;     // 512
    int* slot   = bsum + 512;          // N_EDGES

    hipMemsetAsync(deg, 0, (size_t)N_NODES * sizeof(int), stream);

    const int eblocks = (N_EDGES + 255) / 256;
    degree_hist<<<eblocks, 256, 0, stream>>>(ei, deg);
    scan_block<<<NB, SCAN_B, 0, stream>>>(deg, off, bsum);
    scan_bsum<<<1, 512, 0, stream>>>(bsum);
    scan_add<<<NB, SCAN_B, 0, stream>>>(off, bsum);

    // cursor starts at off[] (d2d copy, stream-ordered)
    hipMemcpyAsync(cursor, off, (size_t)N_NODES * sizeof(int),
                   hipMemcpyDeviceToDevice, stream);
    fill_slots<<<eblocks, 256, 0, stream>>>(ei, cursor, slot);

    const int waves_per_block = 256 / 64;
    const int grid = (N_NODES + waves_per_block - 1) / waves_per_block;
    gine_fused<<<grid, 256, 0, stream>>>(x, off, slot, W1, b1, W2, b2, out);
}

// Round 5
// 363.153 us; speedup vs baseline: 4.1536x; 1.0511x over previous
//
#include <hip/hip_runtime.h>

#define N_NODES 100000
#define N_EDGES 1600000
#define DIM 64

#define SCAN_B 256
#define NB ((N_NODES + SCAN_B - 1) / SCAN_B)   // 391 blocks

// ---------------------------------------------------------------------------
// Kernel A: degree histogram over dst (int atomics on 400 KB, L2-resident)
// 2 edges per thread, int2 loads.
// ---------------------------------------------------------------------------
__global__ __launch_bounds__(256) void degree_hist(
    const int* __restrict__ ei, int* __restrict__ deg)
{
    const int t = blockIdx.x * blockDim.x + threadIdx.x;
    const int e = t * 2;
    if (e + 1 < N_EDGES) {
        const int2 d2 = *reinterpret_cast<const int2*>(ei + N_EDGES + e);
        atomicAdd(&deg[d2.x], 1);
        atomicAdd(&deg[d2.y], 1);
    } else if (e < N_EDGES) {
        atomicAdd(&deg[ei[N_EDGES + e]], 1);
    }
}

// ---------------------------------------------------------------------------
// Scan step 1: per-block exclusive scan of deg -> off, block totals -> bsum
// ---------------------------------------------------------------------------
__global__ __launch_bounds__(SCAN_B) void scan_block(
    const int* __restrict__ deg, int* __restrict__ off, int* __restrict__ bsum)
{
    __shared__ int s[SCAN_B];
    const int t = threadIdx.x;
    const int i = blockIdx.x * SCAN_B + t;
    const int v = (i < N_NODES) ? deg[i] : 0;
    s[t] = v;
    __syncthreads();
    #pragma unroll
    for (int d = 1; d < SCAN_B; d <<= 1) {
        const int add = (t >= d) ? s[t - d] : 0;
        __syncthreads();
        s[t] += add;
        __syncthreads();
    }
    if (i < N_NODES) off[i] = s[t] - v;           // exclusive
    if (t == SCAN_B - 1) bsum[blockIdx.x] = s[t]; // inclusive block total
}

// ---------------------------------------------------------------------------
// Scan step 2: exclusive scan of the 391 block totals (single block)
// ---------------------------------------------------------------------------
__global__ __launch_bounds__(512) void scan_bsum(int* __restrict__ bsum)
{
    __shared__ int s[512];
    const int t = threadIdx.x;
    const int v = (t < NB) ? bsum[t] : 0;
    s[t] = v;
    __syncthreads();
    #pragma unroll
    for (int d = 1; d < 512; d <<= 1) {
        const int add = (t >= d) ? s[t - d] : 0;
        __syncthreads();
        s[t] += add;
        __syncthreads();
    }
    if (t < NB) bsum[t] = s[t] - v;               // exclusive
}

// ---------------------------------------------------------------------------
// Scan step 3: add block offsets; ALSO writes cursor (no SDMA memcpy node —
// a D2D memcpy in a captured graph costs compute<->SDMA sync bubbles)
// ---------------------------------------------------------------------------
__global__ __launch_bounds__(SCAN_B) void scan_add(
    int* __restrict__ off, const int* __restrict__ bsum,
    int* __restrict__ cursor)
{
    const int i = blockIdx.x * SCAN_B + threadIdx.x;
    if (i < N_NODES) {
        const int v = off[i] + bsum[blockIdx.x];
        off[i] = v;
        cursor[i] = v;
    }
    if (i == 0) off[N_NODES] = N_EDGES;
}

// ---------------------------------------------------------------------------
// Kernel C: bucket fill — slot[pos] = src, cursor pre-initialized to off[]
// 2 edges per thread, int2 loads.
// ---------------------------------------------------------------------------
__global__ __launch_bounds__(256) void fill_slots(
    const int* __restrict__ ei,
    int* __restrict__ cursor, int* __restrict__ slot)
{
    const int t = blockIdx.x * blockDim.x + threadIdx.x;
    const int e = t * 2;
    if (e + 1 < N_EDGES) {
        const int2 s2 = *reinterpret_cast<const int2*>(ei + e);
        const int2 d2 = *reinterpret_cast<const int2*>(ei + N_EDGES + e);
        slot[atomicAdd(&cursor[d2.x], 1)] = s2.x;
        slot[atomicAdd(&cursor[d2.y], 1)] = s2.y;
    } else if (e < N_EDGES) {
        const int s = ei[e];
        const int d = ei[N_EDGES + e];
        slot[atomicAdd(&cursor[d], 1)] = s;
    }
}

// ---------------------------------------------------------------------------
// Kernel D: fused aggregate + MLP.  One wave per node.
// Gather: lane -> (group g = lane>>4, chunk c = lane&15). Each 16-lane group
// loads a different edge's full 64-dim row as float4 => one wave-load covers
// 4 edges (1 KB); 8-deep unroll = 32 edges in flight per wave.
// Group partials combined via shfl_xor(16/32), then redistributed to
// lane=dim layout for the shfl-broadcast MLP.
// ---------------------------------------------------------------------------
__global__ __launch_bounds__(256) void gine_fused(
    const float* __restrict__ x,
    const int*   __restrict__ off,
    const int*   __restrict__ slot,
    const float* __restrict__ W1,
    const float* __restrict__ b1,
    const float* __restrict__ W2,
    const float* __restrict__ b2,
    float*       __restrict__ out)
{
    const int wid  = (blockIdx.x * blockDim.x + threadIdx.x) >> 6;
    const int lane = threadIdx.x & 63;
    if (wid >= N_NODES) return;

    const int beg = off[wid];
    const int deg = off[wid + 1] - beg;

    const int g = lane >> 4;        // edge subgroup 0..3
    const int c = lane & 15;        // float4 chunk within the 64-dim row

    const size_t base = (size_t)wid * DIM + lane;
    const float xself = x[base];    // issue early

    float4 acc4 = make_float4(0.f, 0.f, 0.f, 0.f);

    for (int kb = 0; kb < deg; kb += 64) {
        const int nv = min(64, deg - kb);
        // coalesced slot prefetch: lane i holds slot[beg+kb+i]
        const int my = (kb + lane < deg) ? slot[beg + kb + lane] : 0;

        for (int r = 0; r < nv; r += 32) {
            // edge (r + j*4 + g) handled by group g at depth j
            float4 a[8];
            #pragma unroll
            for (int j = 0; j < 8; ++j) {
                const int epos = r + j * 4 + g;
                const int s = __shfl(my, epos, 64);
                if (epos < nv) {
                    a[j] = *reinterpret_cast<const float4*>(
                        x + (size_t)s * DIM + c * 4);
                }
            }
            #pragma unroll
            for (int j = 0; j < 8; ++j) {
                const int epos = r + j * 4 + g;
                if (epos < nv) {
                    acc4.x += fmaxf(a[j].x, 0.f);
                    acc4.y += fmaxf(a[j].y, 0.f);
                    acc4.z += fmaxf(a[j].z, 0.f);
                    acc4.w += fmaxf(a[j].w, 0.f);
                }
            }
        }
    }

    // combine the 4 group partials (lanes xor 16, xor 32)
    acc4.x += __shfl_xor(acc4.x, 16, 64);
    acc4.y += __shfl_xor(acc4.y, 16, 64);
    acc4.z += __shfl_xor(acc4.z, 16, 64);
    acc4.w += __shfl_xor(acc4.w, 16, 64);
    acc4.x += __shfl_xor(acc4.x, 32, 64);
    acc4.y += __shfl_xor(acc4.y, 32, 64);
    acc4.z += __shfl_xor(acc4.z, 32, 64);
    acc4.w += __shfl_xor(acc4.w, 32, 64);

    // redistribute: lane d wants component (d&3) of chunk-lane (d>>2)
    const int cs   = lane >> 2;
    const int comp = lane & 3;
    const float v0 = __shfl(acc4.x, cs, 64);
    const float v1 = __shfl(acc4.y, cs, 64);
    const float v2 = __shfl(acc4.z, cs, 64);
    const float v3 = __shfl(acc4.w, cs, 64);
    const float agg = (comp == 0) ? v0 : (comp == 1) ? v1
                    : (comp == 2) ? v2 : v3;

    const float h = xself + agg;

    float acc = b1[lane];
    #pragma unroll
    for (int i = 0; i < DIM; ++i)
        acc = fmaf(__shfl(h, i, 64), W1[i * DIM + lane], acc);
    const float y = fmaxf(acc, 0.0f);

    float acc2 = b2[lane];
    #pragma unroll
    for (int i = 0; i < DIM; ++i)
        acc2 = fmaf(__shfl(y, i, 64), W2[i * DIM + lane], acc2);

    out[base] = fmaxf(acc2, 0.0f);
}

// ---------------------------------------------------------------------------
extern "C" void kernel_launch(void* const* d_in, const int* in_sizes, int n_in,
                              void* d_out, int out_size, void* d_ws, size_t ws_size,
                              hipStream_t stream) {
    const float* x  = (const float*)d_in[0];
    const int*   ei = (const int*)d_in[1];
    const float* W1 = (const float*)d_in[2];
    const float* b1 = (const float*)d_in[3];
    const float* W2 = (const float*)d_in[4];
    const float* b2 = (const float*)d_in[5];
    float* out = (float*)d_out;

    // workspace layout (ints): deg | off | cursor | bsum | slot
    int* deg    = (int*)d_ws;          // N_NODES
    int* off    = deg + 100352;        // N_NODES + 1
    int* cursor = off + 100352;        // N_NODES
    int* bsum   = cursor + 100352;     // 512
    int* slot   = bsum + 512;          // N_EDGES

    hipMemsetAsync(deg, 0, (size_t)N_NODES * sizeof(int), stream);

    const int eblocks2 = (N_EDGES / 2 + 255) / 256;
    degree_hist<<<eblocks2, 256, 0, stream>>>(ei, deg);
    scan_block<<<NB, SCAN_B, 0, stream>>>(deg, off, bsum);
    scan_bsum<<<1, 512, 0, stream>>>(bsum);
    scan_add<<<NB, SCAN_B, 0, stream>>>(off, bsum, cursor);
    fill_slots<<<eblocks2, 256, 0, stream>>>(ei, cursor, slot);

    const int waves_per_block = 256 / 64;
    const int grid = (N_NODES + waves_per_block - 1) / waves_per_block;
    gine_fused<<<grid, 256, 0, stream>>>(x, off, slot, W1, b1, W2, b2, out);
}

// Round 6
// 303.498 us; speedup vs baseline: 4.9700x; 1.1966x over previous
//
#include <hip/hip_runtime.h>

#define N_NODES 100000
#define N_EDGES 1600000
#define DIM 64

#define SCAN_B 256
#define NB ((N_NODES + SCAN_B - 1) / SCAN_B)   // 391 blocks

// ---- bf16 helpers (hand-rolled, RNE; inputs are finite) --------------------
__device__ __forceinline__ float bflo(unsigned u) {          // low bf16 -> f32
    return __uint_as_float(u << 16);
}
__device__ __forceinline__ float bfhi(unsigned u) {          // high bf16 -> f32
    return __uint_as_float(u & 0xFFFF0000u);
}
__device__ __forceinline__ unsigned f2bf(float f) {          // f32 -> bf16 bits (RNE)
    unsigned u = __float_as_uint(f);
    u += 0x7FFFu + ((u >> 16) & 1u);
    return u >> 16;
}

// ---------------------------------------------------------------------------
// prep: rx = relu(x) as bf16, packed. 4 floats / thread.
// ---------------------------------------------------------------------------
__global__ __launch_bounds__(256) void prep_relu(
    const float* __restrict__ x, unsigned* __restrict__ rx)  // rx as uint pairs
{
    const int i = blockIdx.x * blockDim.x + threadIdx.x;     // per float4
    if (i >= N_NODES * DIM / 4) return;
    const float4 v = reinterpret_cast<const float4*>(x)[i];
    const unsigned a = f2bf(fmaxf(v.x, 0.f));
    const unsigned b = f2bf(fmaxf(v.y, 0.f));
    const unsigned c = f2bf(fmaxf(v.z, 0.f));
    const unsigned d = f2bf(fmaxf(v.w, 0.f));
    uint2 o;
    o.x = a | (b << 16);
    o.y = c | (d << 16);
    reinterpret_cast<uint2*>(rx)[i] = o;
}

// ---------------------------------------------------------------------------
// degree histogram (4 edges / thread)
// ---------------------------------------------------------------------------
__global__ __launch_bounds__(256) void degree_hist(
    const int* __restrict__ ei, int* __restrict__ deg)
{
    const int t = blockIdx.x * blockDim.x + threadIdx.x;
    const int e = t * 4;
    if (e + 3 < N_EDGES) {
        const int4 d4 = *reinterpret_cast<const int4*>(ei + N_EDGES + e);
        atomicAdd(&deg[d4.x], 1);
        atomicAdd(&deg[d4.y], 1);
        atomicAdd(&deg[d4.z], 1);
        atomicAdd(&deg[d4.w], 1);
    } else {
        for (int k = e; k < N_EDGES; ++k) atomicAdd(&deg[ei[N_EDGES + k]], 1);
    }
}

// ---------------------------------------------------------------------------
// scan (3 kernels, unchanged)
// ---------------------------------------------------------------------------
__global__ __launch_bounds__(SCAN_B) void scan_block(
    const int* __restrict__ deg, int* __restrict__ off, int* __restrict__ bsum)
{
    __shared__ int s[SCAN_B];
    const int t = threadIdx.x;
    const int i = blockIdx.x * SCAN_B + t;
    const int v = (i < N_NODES) ? deg[i] : 0;
    s[t] = v;
    __syncthreads();
    #pragma unroll
    for (int d = 1; d < SCAN_B; d <<= 1) {
        const int add = (t >= d) ? s[t - d] : 0;
        __syncthreads();
        s[t] += add;
        __syncthreads();
    }
    if (i < N_NODES) off[i] = s[t] - v;
    if (t == SCAN_B - 1) bsum[blockIdx.x] = s[t];
}

__global__ __launch_bounds__(512) void scan_bsum(int* __restrict__ bsum)
{
    __shared__ int s[512];
    const int t = threadIdx.x;
    const int v = (t < NB) ? bsum[t] : 0;
    s[t] = v;
    __syncthreads();
    #pragma unroll
    for (int d = 1; d < 512; d <<= 1) {
        const int add = (t >= d) ? s[t - d] : 0;
        __syncthreads();
        s[t] += add;
        __syncthreads();
    }
    if (t < NB) bsum[t] = s[t] - v;
}

__global__ __launch_bounds__(SCAN_B) void scan_add(
    int* __restrict__ off, const int* __restrict__ bsum,
    int* __restrict__ cursor)
{
    const int i = blockIdx.x * SCAN_B + threadIdx.x;
    if (i < N_NODES) {
        const int v = off[i] + bsum[blockIdx.x];
        off[i] = v;
        cursor[i] = v;
    }
    if (i == 0) off[N_NODES] = N_EDGES;
}

// ---------------------------------------------------------------------------
// bucket fill (4 edges / thread)
// ---------------------------------------------------------------------------
__global__ __launch_bounds__(256) void fill_slots(
    const int* __restrict__ ei,
    int* __restrict__ cursor, int* __restrict__ slot)
{
    const int t = blockIdx.x * blockDim.x + threadIdx.x;
    const int e = t * 4;
    if (e + 3 < N_EDGES) {
        const int4 s4 = *reinterpret_cast<const int4*>(ei + e);
        const int4 d4 = *reinterpret_cast<const int4*>(ei + N_EDGES + e);
        slot[atomicAdd(&cursor[d4.x], 1)] = s4.x;
        slot[atomicAdd(&cursor[d4.y], 1)] = s4.y;
        slot[atomicAdd(&cursor[d4.z], 1)] = s4.z;
        slot[atomicAdd(&cursor[d4.w], 1)] = s4.w;
    } else {
        for (int k = e; k < N_EDGES; ++k) {
            const int sv = ei[k];
            const int dv = ei[N_EDGES + k];
            slot[atomicAdd(&cursor[dv], 1)] = sv;
        }
    }
}

// ---------------------------------------------------------------------------
// gather_h: wave per node. bf16 rows (128 B = ONE cache line per edge).
// lane -> (gsub = lane&7 : edge subgroup, chunk = lane>>3 : 16B of the row).
// One wave-inst loads 8 edges' rows. All row loads for a 64-slot batch are
// issued before consumption. Writes h = x + agg as bf16 (paired stores).
// ---------------------------------------------------------------------------
__global__ __launch_bounds__(256) void gather_h(
    const float*  __restrict__ x,
    const unsigned char* __restrict__ rx,    // bf16 rows, 128 B each
    const int*    __restrict__ off,
    const int*    __restrict__ slot,
    unsigned*     __restrict__ hbuf)         // bf16 pairs
{
    const int wid  = (blockIdx.x * blockDim.x + threadIdx.x) >> 6;
    const int lane = threadIdx.x & 63;
    if (wid >= N_NODES) return;

    const int beg = off[wid];
    const int deg = off[wid + 1] - beg;

    const int gsub      = lane & 7;
    const int chunkByte = (lane >> 3) * 16;

    const float xself = x[(size_t)wid * DIM + lane];

    float acc[8];
    #pragma unroll
    for (int e = 0; e < 8; ++e) acc[e] = 0.f;

    for (int kb = 0; kb < deg; kb += 64) {
        const int nv = min(64, deg - kb);
        const int my = (kb + lane < deg) ? slot[beg + kb + lane] : 0;

        uint4 buf[8];
        #pragma unroll
        for (int j = 0; j < 8; ++j) {
            if (j * 8 < nv) {                       // wave-uniform guard
                const int s = __shfl(my, j * 8 + gsub, 64);
                buf[j] = *reinterpret_cast<const uint4*>(
                    rx + (size_t)s * 128 + chunkByte);
            }
        }
        #pragma unroll
        for (int j = 0; j < 8; ++j) {
            if (j * 8 < nv) {
                if (j * 8 + gsub < nv) {            // per-lane validity
                    acc[0] += bflo(buf[j].x); acc[1] += bfhi(buf[j].x);
                    acc[2] += bflo(buf[j].y); acc[3] += bfhi(buf[j].y);
                    acc[4] += bflo(buf[j].z); acc[5] += bfhi(buf[j].z);
                    acc[6] += bflo(buf[j].w); acc[7] += bfhi(buf[j].w);
                }
            }
        }
    }

    // reduce the 8 edge-subgroups (lanes differing in bits 0..2)
    #pragma unroll
    for (int m = 1; m < 8; m <<= 1) {
        #pragma unroll
        for (int e = 0; e < 8; ++e) acc[e] += __shfl_xor(acc[e], m, 64);
    }

    // lane holds chunk (lane>>3): select element (lane&7) via cndmask tree
    const float s0 = (gsub & 1) ? acc[1] : acc[0];
    const float s1 = (gsub & 1) ? acc[3] : acc[2];
    const float s2 = (gsub & 1) ? acc[5] : acc[4];
    const float s3 = (gsub & 1) ? acc[7] : acc[6];
    const float t0 = (gsub & 2) ? s1 : s0;
    const float t1 = (gsub & 2) ? s3 : s2;
    const float agg = (gsub & 4) ? t1 : t0;

    const float h = xself + agg;

    // pack pairs: even lane stores (h_lane, h_lane+1) as one uint
    const float hnext = __shfl_down(h, 1, 64);
    if (!(lane & 1)) {
        const unsigned lo = f2bf(h);
        const unsigned hi = f2bf(hnext);
        hbuf[((size_t)wid * DIM + lane) >> 1] = lo | (hi << 16);
    }
}

// ---------------------------------------------------------------------------
// mlp8: one wave processes 8 nodes -> each W column load reused 8x.
// h broadcast via readlane (SGPR operand in the FMA).
// ---------------------------------------------------------------------------
__device__ __forceinline__ float lanebcast(float v, int i) {
    return __uint_as_float(__builtin_amdgcn_readlane(__float_as_uint(v), i));
}

__global__ __launch_bounds__(256) void mlp8(
    const unsigned short* __restrict__ hbuf,
    const float* __restrict__ W1, const float* __restrict__ b1,
    const float* __restrict__ W2, const float* __restrict__ b2,
    float* __restrict__ out)
{
    const int wv   = (blockIdx.x * blockDim.x + threadIdx.x) >> 6;
    const int lane = threadIdx.x & 63;
    const int n0   = wv * 8;
    if (n0 >= N_NODES) return;

    float h[8];
    #pragma unroll
    for (int b = 0; b < 8; ++b) {
        const int n = n0 + b;
        h[b] = (n < N_NODES)
             ? __uint_as_float((unsigned)hbuf[(size_t)n * DIM + lane] << 16)
             : 0.f;
    }

    float acc[8];
    #pragma unroll
    for (int b = 0; b < 8; ++b) acc[b] = b1[lane];
    #pragma unroll
    for (int i = 0; i < DIM; ++i) {
        const float w = W1[i * DIM + lane];
        #pragma unroll
        for (int b = 0; b < 8; ++b)
            acc[b] = fmaf(lanebcast(h[b], i), w, acc[b]);
    }
    float y[8];
    #pragma unroll
    for (int b = 0; b < 8; ++b) y[b] = fmaxf(acc[b], 0.f);

    float acc2[8];
    #pragma unroll
    for (int b = 0; b < 8; ++b) acc2[b] = b2[lane];
    #pragma unroll
    for (int i = 0; i < DIM; ++i) {
        const float w = W2[i * DIM + lane];
        #pragma unroll
        for (int b = 0; b < 8; ++b)
            acc2[b] = fmaf(lanebcast(y[b], i), w, acc2[b]);
    }

    #pragma unroll
    for (int b = 0; b < 8; ++b) {
        const int n = n0 + b;
        if (n < N_NODES)
            out[(size_t)n * DIM + lane] = fmaxf(acc2[b], 0.f);
    }
}

// ---------------------------------------------------------------------------
extern "C" void kernel_launch(void* const* d_in, const int* in_sizes, int n_in,
                              void* d_out, int out_size, void* d_ws, size_t ws_size,
                              hipStream_t stream) {
    const float* x  = (const float*)d_in[0];
    const int*   ei = (const int*)d_in[1];
    const float* W1 = (const float*)d_in[2];
    const float* b1 = (const float*)d_in[3];
    const float* W2 = (const float*)d_in[4];
    const float* b2 = (const float*)d_in[5];
    float* out = (float*)d_out;

    // rx (relu(x) in bf16, 12.8 MB) lives in the FIRST HALF of d_out; it is
    // fully consumed by gather_h before mlp8 overwrites all of d_out.
    unsigned* rx = (unsigned*)d_out;

    // workspace (ints): deg | off | cursor | bsum | slot | hbuf(bf16)
    int* deg    = (int*)d_ws;          // N_NODES
    int* off    = deg + 100352;        // N_NODES + 1
    int* cursor = off + 100352;        // N_NODES
    int* bsum   = cursor + 100352;     // 512
    int* slot   = bsum + 512;          // N_EDGES
    unsigned* hbuf = (unsigned*)(slot + N_EDGES);  // N_NODES*DIM bf16 = 12.8 MB

    hipMemsetAsync(deg, 0, (size_t)N_NODES * sizeof(int), stream);

    prep_relu<<<(N_NODES * DIM / 4 + 255) / 256, 256, 0, stream>>>(x, rx);

    const int eblocks4 = (N_EDGES / 4 + 255) / 256;
    degree_hist<<<eblocks4, 256, 0, stream>>>(ei, deg);
    scan_block<<<NB, SCAN_B, 0, stream>>>(deg, off, bsum);
    scan_bsum<<<1, 512, 0, stream>>>(bsum);
    scan_add<<<NB, SCAN_B, 0, stream>>>(off, bsum, cursor);
    fill_slots<<<eblocks4, 256, 0, stream>>>(ei, cursor, slot);

    gather_h<<<(N_NODES + 3) / 4, 256, 0, stream>>>(
        x, (const unsigned char*)rx, off, slot, hbuf);

    mlp8<<<(N_NODES / 8 + 3) / 4, 256, 0, stream>>>(
        (const unsigned short*)hbuf, W1, b1, W2, b2, out);
}

// Round 7
// 219.153 us; speedup vs baseline: 6.8828x; 1.3849x over previous
//
#include <hip/hip_runtime.h>

#define N_NODES 100000
#define N_EDGES 1600000
#define DIM 64

#define SCAN_B 256
#define NB ((N_NODES + SCAN_B - 1) / SCAN_B)   // 391 blocks

#define BIN_SHIFT 9
#define BIN_NODES 512
#define NBINS ((N_NODES + BIN_NODES - 1) / BIN_NODES)   // 196
#define TILE_A 4096
#define NBLK_A ((N_EDGES + TILE_A - 1) / TILE_A)        // 391
#define CAP_B 9216          // >> mean 8192 + 6 sigma (~90)

// ---- bf16 helpers (hand-rolled, RNE; inputs are finite) --------------------
__device__ __forceinline__ float bflo(unsigned u) { return __uint_as_float(u << 16); }
__device__ __forceinline__ float bfhi(unsigned u) { return __uint_as_float(u & 0xFFFF0000u); }
__device__ __forceinline__ unsigned f2bf(float f) {
    unsigned u = __float_as_uint(f);
    u += 0x7FFFu + ((u >> 16) & 1u);
    return u >> 16;
}

// ---------------------------------------------------------------------------
// prep: rx = relu(x) as bf16, packed. 4 floats / thread.
// ---------------------------------------------------------------------------
__global__ __launch_bounds__(256) void prep_relu(
    const float* __restrict__ x, unsigned* __restrict__ rx)
{
    const int i = blockIdx.x * blockDim.x + threadIdx.x;
    if (i >= N_NODES * DIM / 4) return;
    const float4 v = reinterpret_cast<const float4*>(x)[i];
    uint2 o;
    o.x = f2bf(fmaxf(v.x, 0.f)) | (f2bf(fmaxf(v.y, 0.f)) << 16);
    o.y = f2bf(fmaxf(v.z, 0.f)) | (f2bf(fmaxf(v.w, 0.f)) << 16);
    reinterpret_cast<uint2*>(rx)[i] = o;
}

// ---------------------------------------------------------------------------
// degree histogram (4 edges / thread)
// ---------------------------------------------------------------------------
__global__ __launch_bounds__(256) void degree_hist(
    const int* __restrict__ ei, int* __restrict__ deg)
{
    const int t = blockIdx.x * blockDim.x + threadIdx.x;
    const int e = t * 4;
    if (e + 3 < N_EDGES) {
        const int4 d4 = *reinterpret_cast<const int4*>(ei + N_EDGES + e);
        atomicAdd(&deg[d4.x], 1);
        atomicAdd(&deg[d4.y], 1);
        atomicAdd(&deg[d4.z], 1);
        atomicAdd(&deg[d4.w], 1);
    } else {
        for (int k = e; k < N_EDGES; ++k) atomicAdd(&deg[ei[N_EDGES + k]], 1);
    }
}

// ---------------------------------------------------------------------------
// scan (3 kernels)
// ---------------------------------------------------------------------------
__global__ __launch_bounds__(SCAN_B) void scan_block(
    const int* __restrict__ deg, int* __restrict__ off, int* __restrict__ bsum)
{
    __shared__ int s[SCAN_B];
    const int t = threadIdx.x;
    const int i = blockIdx.x * SCAN_B + t;
    const int v = (i < N_NODES) ? deg[i] : 0;
    s[t] = v;
    __syncthreads();
    #pragma unroll
    for (int d = 1; d < SCAN_B; d <<= 1) {
        const int add = (t >= d) ? s[t - d] : 0;
        __syncthreads();
        s[t] += add;
        __syncthreads();
    }
    if (i < N_NODES) off[i] = s[t] - v;
    if (t == SCAN_B - 1) bsum[blockIdx.x] = s[t];
}

__global__ __launch_bounds__(512) void scan_bsum(int* __restrict__ bsum)
{
    __shared__ int s[512];
    const int t = threadIdx.x;
    const int v = (t < NB) ? bsum[t] : 0;
    s[t] = v;
    __syncthreads();
    #pragma unroll
    for (int d = 1; d < 512; d <<= 1) {
        const int add = (t >= d) ? s[t - d] : 0;
        __syncthreads();
        s[t] += add;
        __syncthreads();
    }
    if (t < NB) bsum[t] = s[t] - v;
}

__global__ __launch_bounds__(SCAN_B) void scan_add(
    int* __restrict__ off, const int* __restrict__ bsum)
{
    const int i = blockIdx.x * SCAN_B + threadIdx.x;
    if (i < N_NODES) off[i] += bsum[blockIdx.x];
    if (i == 0) off[N_NODES] = N_EDGES;
}

// ---------------------------------------------------------------------------
// binseed: per-bin global cursor starts at the bin's CSR region base
// ---------------------------------------------------------------------------
__global__ __launch_bounds__(256) void binseed(
    const int* __restrict__ off, int* __restrict__ gcur)
{
    const int b = blockIdx.x * blockDim.x + threadIdx.x;
    if (b < NBINS) gcur[b] = off[b << BIN_SHIFT];
}

// ---------------------------------------------------------------------------
// Pass A: binscatter. Block stages TILE_A edges in LDS grouped by coarse bin
// (dst>>9), allocates one contiguous run per bin via global atomic, streams
// out packed entries (src<<9 | dst&511). Runs ~21 entries => write-combining
// instead of 17x partial-line writeback.
// ---------------------------------------------------------------------------
__global__ __launch_bounds__(256) void binscatter(
    const int* __restrict__ ei,
    int* __restrict__ gcur,
    unsigned* __restrict__ binned)
{
    __shared__ int lhist[NBINS];
    __shared__ int lbase[NBINS];
    __shared__ int lcur[NBINS];
    __shared__ int ldelta[NBINS];
    __shared__ int ls[256];
    __shared__ unsigned staged[TILE_A];
    __shared__ unsigned char sbin[TILE_A];

    const int t  = threadIdx.x;
    const int e0 = blockIdx.x * TILE_A;
    const int n  = min(TILE_A, N_EDGES - e0);

    for (int i = t; i < NBINS; i += 256) { lhist[i] = 0; lcur[i] = 0; }
    __syncthreads();

    int      mybin[TILE_A / 256];
    unsigned myval[TILE_A / 256];
    #pragma unroll
    for (int j = 0; j < TILE_A / 256; ++j) {
        const int idx = t + j * 256;
        if (idx < n) {
            const int s = ei[e0 + idx];
            const int d = ei[N_EDGES + e0 + idx];
            mybin[j] = d >> BIN_SHIFT;
            myval[j] = ((unsigned)s << BIN_SHIFT) | (unsigned)(d & (BIN_NODES - 1));
            atomicAdd(&lhist[mybin[j]], 1);
        } else {
            mybin[j] = -1;
        }
    }
    __syncthreads();

    // exclusive scan of lhist -> lbase (NBINS <= 256)
    ls[t] = (t < NBINS) ? lhist[t] : 0;
    __syncthreads();
    #pragma unroll
    for (int d = 1; d < 256; d <<= 1) {
        const int add = (t >= d) ? ls[t - d] : 0;
        __syncthreads();
        ls[t] += add;
        __syncthreads();
    }
    if (t < NBINS) lbase[t] = ls[t] - lhist[t];
    __syncthreads();

    // allocate global runs
    if (t < NBINS) {
        const int c = lhist[t];
        ldelta[t] = (c > 0) ? (atomicAdd(&gcur[t], c) - lbase[t]) : 0;
    }
    __syncthreads();

    // stage into LDS grouped by bin
    #pragma unroll
    for (int j = 0; j < TILE_A / 256; ++j) {
        if (mybin[j] >= 0) {
            const int p = lbase[mybin[j]] + atomicAdd(&lcur[mybin[j]], 1);
            staged[p] = myval[j];
            sbin[p]   = (unsigned char)mybin[j];
        }
    }
    __syncthreads();

    // stream out: consecutive p within a bin-run -> consecutive global dest
    for (int p = t; p < n; p += 256)
        binned[p + ldelta[sbin[p]]] = staged[p];
}

// ---------------------------------------------------------------------------
// Pass B: binsort. One block per bin: read the bin's contiguous packed
// entries, exact per-node LDS scatter (final CSR order), stream out
// full-line coalesced.
// ---------------------------------------------------------------------------
__global__ __launch_bounds__(256) void binsort(
    const unsigned* __restrict__ binned,
    const int* __restrict__ off,
    int* __restrict__ slot)
{
    __shared__ int lofs[BIN_NODES];
    __shared__ int lcur[BIN_NODES];
    __shared__ int sseg[CAP_B];

    const int b     = blockIdx.x;
    const int node0 = b << BIN_SHIFT;
    const int nloc  = min(BIN_NODES, N_NODES - node0);
    const int rbase = off[node0];
    const int cnt   = off[node0 + nloc] - rbase;
    const int t     = threadIdx.x;

    for (int i = t; i < nloc; i += 256) {
        lofs[i] = off[node0 + i] - rbase;
        lcur[i] = 0;
    }
    __syncthreads();

    if (cnt <= CAP_B) {
        for (int p = t; p < cnt; p += 256) {
            const unsigned v = binned[rbase + p];
            const int dl  = v & (BIN_NODES - 1);
            const int rel = lofs[dl] + atomicAdd(&lcur[dl], 1);
            sseg[rel] = (int)(v >> BIN_SHIFT);
        }
        __syncthreads();
        for (int p = t; p < cnt; p += 256)
            slot[rbase + p] = sseg[p];
    } else {
        // statistically unreachable fallback (correct, uncoalesced)
        for (int p = t; p < cnt; p += 256) {
            const unsigned v = binned[rbase + p];
            const int dl  = v & (BIN_NODES - 1);
            const int rel = lofs[dl] + atomicAdd(&lcur[dl], 1);
            slot[rbase + rel] = (int)(v >> BIN_SHIFT);
        }
    }
}

// ---------------------------------------------------------------------------
// gather_h: wave per node. bf16 rows (128 B = ONE cache line per edge).
// ---------------------------------------------------------------------------
__global__ __launch_bounds__(256) void gather_h(
    const float*  __restrict__ x,
    const unsigned char* __restrict__ rx,
    const int*    __restrict__ off,
    const int*    __restrict__ slot,
    unsigned*     __restrict__ hbuf)
{
    const int wid  = (blockIdx.x * blockDim.x + threadIdx.x) >> 6;
    const int lane = threadIdx.x & 63;
    if (wid >= N_NODES) return;

    const int beg = off[wid];
    const int deg = off[wid + 1] - beg;

    const int gsub      = lane & 7;
    const int chunkByte = (lane >> 3) * 16;

    const float xself = x[(size_t)wid * DIM + lane];

    float acc[8];
    #pragma unroll
    for (int e = 0; e < 8; ++e) acc[e] = 0.f;

    for (int kb = 0; kb < deg; kb += 64) {
        const int nv = min(64, deg - kb);
        const int my = (kb + lane < deg) ? slot[beg + kb + lane] : 0;

        uint4 buf[8];
        #pragma unroll
        for (int j = 0; j < 8; ++j) {
            if (j * 8 < nv) {
                const int s = __shfl(my, j * 8 + gsub, 64);
                buf[j] = *reinterpret_cast<const uint4*>(
                    rx + (size_t)s * 128 + chunkByte);
            }
        }
        #pragma unroll
        for (int j = 0; j < 8; ++j) {
            if (j * 8 < nv) {
                if (j * 8 + gsub < nv) {
                    acc[0] += bflo(buf[j].x); acc[1] += bfhi(buf[j].x);
                    acc[2] += bflo(buf[j].y); acc[3] += bfhi(buf[j].y);
                    acc[4] += bflo(buf[j].z); acc[5] += bfhi(buf[j].z);
                    acc[6] += bflo(buf[j].w); acc[7] += bfhi(buf[j].w);
                }
            }
        }
    }

    #pragma unroll
    for (int m = 1; m < 8; m <<= 1) {
        #pragma unroll
        for (int e = 0; e < 8; ++e) acc[e] += __shfl_xor(acc[e], m, 64);
    }

    const float s0 = (gsub & 1) ? acc[1] : acc[0];
    const float s1 = (gsub & 1) ? acc[3] : acc[2];
    const float s2 = (gsub & 1) ? acc[5] : acc[4];
    const float s3 = (gsub & 1) ? acc[7] : acc[6];
    const float t0 = (gsub & 2) ? s1 : s0;
    const float t1 = (gsub & 2) ? s3 : s2;
    const float agg = (gsub & 4) ? t1 : t0;

    const float h = xself + agg;

    const float hnext = __shfl_down(h, 1, 64);
    if (!(lane & 1)) {
        hbuf[((size_t)wid * DIM + lane) >> 1] = f2bf(h) | (f2bf(hnext) << 16);
    }
}

// ---------------------------------------------------------------------------
// mlp8: one wave processes 8 nodes -> each W column load reused 8x.
// ---------------------------------------------------------------------------
__device__ __forceinline__ float lanebcast(float v, int i) {
    return __uint_as_float(__builtin_amdgcn_readlane(__float_as_uint(v), i));
}

__global__ __launch_bounds__(256) void mlp8(
    const unsigned short* __restrict__ hbuf,
    const float* __restrict__ W1, const float* __restrict__ b1,
    const float* __restrict__ W2, const float* __restrict__ b2,
    float* __restrict__ out)
{
    const int wv   = (blockIdx.x * blockDim.x + threadIdx.x) >> 6;
    const int lane = threadIdx.x & 63;
    const int n0   = wv * 8;
    if (n0 >= N_NODES) return;

    float h[8];
    #pragma unroll
    for (int b = 0; b < 8; ++b) {
        const int n = n0 + b;
        h[b] = (n < N_NODES)
             ? __uint_as_float((unsigned)hbuf[(size_t)n * DIM + lane] << 16)
             : 0.f;
    }

    float acc[8];
    #pragma unroll
    for (int b = 0; b < 8; ++b) acc[b] = b1[lane];
    #pragma unroll
    for (int i = 0; i < DIM; ++i) {
        const float w = W1[i * DIM + lane];
        #pragma unroll
        for (int b = 0; b < 8; ++b)
            acc[b] = fmaf(lanebcast(h[b], i), w, acc[b]);
    }
    float y[8];
    #pragma unroll
    for (int b = 0; b < 8; ++b) y[b] = fmaxf(acc[b], 0.f);

    float acc2[8];
    #pragma unroll
    for (int b = 0; b < 8; ++b) acc2[b] = b2[lane];
    #pragma unroll
    for (int i = 0; i < DIM; ++i) {
        const float w = W2[i * DIM + lane];
        #pragma unroll
        for (int b = 0; b < 8; ++b)
            acc2[b] = fmaf(lanebcast(y[b], i), w, acc2[b]);
    }

    #pragma unroll
    for (int b = 0; b < 8; ++b) {
        const int n = n0 + b;
        if (n < N_NODES)
            out[(size_t)n * DIM + lane] = fmaxf(acc2[b], 0.f);
    }
}

// ---------------------------------------------------------------------------
extern "C" void kernel_launch(void* const* d_in, const int* in_sizes, int n_in,
                              void* d_out, int out_size, void* d_ws, size_t ws_size,
                              hipStream_t stream) {
    const float* x  = (const float*)d_in[0];
    const int*   ei = (const int*)d_in[1];
    const float* W1 = (const float*)d_in[2];
    const float* b1 = (const float*)d_in[3];
    const float* W2 = (const float*)d_in[4];
    const float* b2 = (const float*)d_in[5];
    float* out = (float*)d_out;

    // rx (relu(x) in bf16, 12.8 MB) lives in d_out; fully consumed by gather_h
    // before mlp8 overwrites d_out.
    unsigned* rx = (unsigned*)d_out;

    // workspace (ints): deg | off | bsum | gcur | slot | hbuf
    // binned aliases hbuf (binned dead before gather_h writes hbuf).
    int* deg  = (int*)d_ws;            // N_NODES
    int* off  = deg + 100352;          // N_NODES + 1
    int* bsum = off + 100352;          // 512
    int* gcur = bsum + 512;            // NBINS (256 padded)
    int* slot = gcur + 256;            // N_EDGES
    unsigned* hbuf   = (unsigned*)(slot + N_EDGES);  // N_NODES*DIM bf16
    unsigned* binned = hbuf;                         // N_EDGES uints (alias)

    hipMemsetAsync(deg, 0, (size_t)N_NODES * sizeof(int), stream);

    prep_relu<<<(N_NODES * DIM / 4 + 255) / 256, 256, 0, stream>>>(x, rx);

    const int eblocks4 = (N_EDGES / 4 + 255) / 256;
    degree_hist<<<eblocks4, 256, 0, stream>>>(ei, deg);
    scan_block<<<NB, SCAN_B, 0, stream>>>(deg, off, bsum);
    scan_bsum<<<1, 512, 0, stream>>>(bsum);
    scan_add<<<NB, SCAN_B, 0, stream>>>(off, bsum);

    binseed<<<1, 256, 0, stream>>>(off, gcur);
    binscatter<<<NBLK_A, 256, 0, stream>>>(ei, gcur, binned);
    binsort<<<NBINS, 256, 0, stream>>>(binned, off, slot);

    gather_h<<<(N_NODES + 3) / 4, 256, 0, stream>>>(
        x, (const unsigned char*)rx, off, slot, hbuf);

    mlp8<<<(N_NODES / 8 + 3) / 4, 256, 0, stream>>>(
        (const unsigned short*)hbuf, W1, b1, W2, b2, out);
}

// Round 8
// 182.665 us; speedup vs baseline: 8.2576x; 1.1998x over previous
//
#include <hip/hip_runtime.h>

#define N_NODES 100000
#define N_EDGES 1600000
#define DIM 64

#define BIN_SHIFT 9
#define BIN_NODES 512
#define NBINS ((N_NODES + BIN_NODES - 1) / BIN_NODES)   // 196
#define TILE_A 4096
#define NBLK_A ((N_EDGES + TILE_A - 1) / TILE_A)        // 391
#define CAP_B 9216          // mean 8192 + ~11 sigma

// ---- bf16 helpers (hand-rolled, RNE; inputs are finite) --------------------
__device__ __forceinline__ float bflo(unsigned u) { return __uint_as_float(u << 16); }
__device__ __forceinline__ float bfhi(unsigned u) { return __uint_as_float(u & 0xFFFF0000u); }
__device__ __forceinline__ unsigned f2bf(float f) {
    unsigned u = __float_as_uint(f);
    u += 0x7FFFu + ((u >> 16) & 1u);
    return u >> 16;
}

// ---------------------------------------------------------------------------
// prep: rx = relu(x) as bf16, packed. 4 floats / thread.
// ---------------------------------------------------------------------------
__global__ __launch_bounds__(256) void prep_relu(
    const float* __restrict__ x, unsigned* __restrict__ rx)
{
    const int i = blockIdx.x * blockDim.x + threadIdx.x;
    if (i >= N_NODES * DIM / 4) return;
    const float4 v = reinterpret_cast<const float4*>(x)[i];
    uint2 o;
    o.x = f2bf(fmaxf(v.x, 0.f)) | (f2bf(fmaxf(v.y, 0.f)) << 16);
    o.y = f2bf(fmaxf(v.z, 0.f)) | (f2bf(fmaxf(v.w, 0.f)) << 16);
    reinterpret_cast<uint2*>(rx)[i] = o;
}

// ---------------------------------------------------------------------------
// bincount: coarse-bin histogram via LDS aggregation. One global atomic per
// (block, nonzero bin) -> ~300K atomics on 784 B instead of 1.6M on 400 KB.
// ---------------------------------------------------------------------------
__global__ __launch_bounds__(256) void bincount(
    const int* __restrict__ ei, int* __restrict__ binc)
{
    __shared__ int lh[NBINS];
    for (int i = threadIdx.x; i < NBINS; i += 256) lh[i] = 0;
    __syncthreads();
    const int t = blockIdx.x * blockDim.x + threadIdx.x;
    const int e = t * 4;
    if (e + 3 < N_EDGES) {
        const int4 d4 = *reinterpret_cast<const int4*>(ei + N_EDGES + e);
        atomicAdd(&lh[d4.x >> BIN_SHIFT], 1);
        atomicAdd(&lh[d4.y >> BIN_SHIFT], 1);
        atomicAdd(&lh[d4.z >> BIN_SHIFT], 1);
        atomicAdd(&lh[d4.w >> BIN_SHIFT], 1);
    } else {
        for (int k = e; k < N_EDGES; ++k)
            atomicAdd(&lh[ei[N_EDGES + k] >> BIN_SHIFT], 1);
    }
    __syncthreads();
    for (int i = threadIdx.x; i < NBINS; i += 256)
        if (lh[i]) atomicAdd(&binc[i], lh[i]);
}

// ---------------------------------------------------------------------------
// binscan: single block scans the 196 bin counts -> binbase; seeds gcur.
// ---------------------------------------------------------------------------
__global__ __launch_bounds__(256) void binscan(
    const int* __restrict__ binc, int* __restrict__ binbase,
    int* __restrict__ gcur)
{
    __shared__ int s[256];
    const int t = threadIdx.x;
    const int v = (t < NBINS) ? binc[t] : 0;
    s[t] = v;
    __syncthreads();
    #pragma unroll
    for (int d = 1; d < 256; d <<= 1) {
        const int add = (t >= d) ? s[t - d] : 0;
        __syncthreads();
        s[t] += add;
        __syncthreads();
    }
    if (t < NBINS) {
        const int base = s[t] - v;
        binbase[t] = base;
        gcur[t]    = base;
    }
    if (t == 0) binbase[NBINS] = N_EDGES;
}

// ---------------------------------------------------------------------------
// Pass A: binscatter. Block stages TILE_A edges in LDS grouped by coarse bin
// (dst>>9), allocates one contiguous run per bin via global atomic, streams
// out packed entries (src<<9 | dst&511).
// ---------------------------------------------------------------------------
__global__ __launch_bounds__(256) void binscatter(
    const int* __restrict__ ei,
    int* __restrict__ gcur,
    unsigned* __restrict__ binned)
{
    __shared__ int lhist[NBINS];
    __shared__ int lbase[NBINS];
    __shared__ int lcur[NBINS];
    __shared__ int ldelta[NBINS];
    __shared__ int ls[256];
    __shared__ unsigned staged[TILE_A];
    __shared__ unsigned char sbin[TILE_A];

    const int t  = threadIdx.x;
    const int e0 = blockIdx.x * TILE_A;
    const int n  = min(TILE_A, N_EDGES - e0);

    for (int i = t; i < NBINS; i += 256) { lhist[i] = 0; lcur[i] = 0; }
    __syncthreads();

    int      mybin[TILE_A / 256];
    unsigned myval[TILE_A / 256];
    #pragma unroll
    for (int j = 0; j < TILE_A / 256; ++j) {
        const int idx = t + j * 256;
        if (idx < n) {
            const int s = ei[e0 + idx];
            const int d = ei[N_EDGES + e0 + idx];
            mybin[j] = d >> BIN_SHIFT;
            myval[j] = ((unsigned)s << BIN_SHIFT) | (unsigned)(d & (BIN_NODES - 1));
            atomicAdd(&lhist[mybin[j]], 1);
        } else {
            mybin[j] = -1;
        }
    }
    __syncthreads();

    ls[t] = (t < NBINS) ? lhist[t] : 0;
    __syncthreads();
    #pragma unroll
    for (int d = 1; d < 256; d <<= 1) {
        const int add = (t >= d) ? ls[t - d] : 0;
        __syncthreads();
        ls[t] += add;
        __syncthreads();
    }
    if (t < NBINS) lbase[t] = ls[t] - lhist[t];
    __syncthreads();

    if (t < NBINS) {
        const int c = lhist[t];
        ldelta[t] = (c > 0) ? (atomicAdd(&gcur[t], c) - lbase[t]) : 0;
    }
    __syncthreads();

    #pragma unroll
    for (int j = 0; j < TILE_A / 256; ++j) {
        if (mybin[j] >= 0) {
            const int p = lbase[mybin[j]] + atomicAdd(&lcur[mybin[j]], 1);
            staged[p] = myval[j];
            sbin[p]   = (unsigned char)mybin[j];
        }
    }
    __syncthreads();

    for (int p = t; p < n; p += 256)
        binned[p + ldelta[sbin[p]]] = staged[p];
}

// ---------------------------------------------------------------------------
// Pass B: binsort. One block per bin. Computes its own 512 node degrees in
// LDS (replaces the global degree_hist + 100K scan), writes the off[]
// segment, LDS-sorts the entries into final CSR order, streams out coalesced.
// ---------------------------------------------------------------------------
__global__ __launch_bounds__(256) void binsort(
    const unsigned* __restrict__ binned,
    const int* __restrict__ binbase,
    int* __restrict__ off,
    int* __restrict__ slot)
{
    __shared__ int lhist[BIN_NODES];
    __shared__ int lofs[BIN_NODES];
    __shared__ int lcur[BIN_NODES];
    __shared__ int ls[256];
    __shared__ int sseg[CAP_B];

    const int b     = blockIdx.x;
    const int node0 = b << BIN_SHIFT;
    const int nloc  = min(BIN_NODES, N_NODES - node0);
    const int rbase = binbase[b];
    const int cnt   = binbase[b + 1] - rbase;
    const int t     = threadIdx.x;

    for (int i = t; i < BIN_NODES; i += 256) { lhist[i] = 0; lcur[i] = 0; }
    __syncthreads();

    // pass 1: per-node degree histogram (LDS atomics, block-exclusive)
    for (int p = t; p < cnt; p += 256)
        atomicAdd(&lhist[binned[rbase + p] & (BIN_NODES - 1)], 1);
    __syncthreads();

    // exclusive scan over 512 counts, pair-per-thread
    const int a0 = lhist[2 * t];
    const int a1 = lhist[2 * t + 1];
    const int ps = a0 + a1;
    ls[t] = ps;
    __syncthreads();
    #pragma unroll
    for (int d = 1; d < 256; d <<= 1) {
        const int add = (t >= d) ? ls[t - d] : 0;
        __syncthreads();
        ls[t] += add;
        __syncthreads();
    }
    const int pbase = ls[t] - ps;
    lofs[2 * t]     = pbase;
    lofs[2 * t + 1] = pbase + a0;
    __syncthreads();

    // write the off[] segment (coalesced, block-exclusive)
    for (int i = t; i < nloc; i += 256)
        off[node0 + i] = rbase + lofs[i];
    if (b == NBINS - 1 && t == 0) off[N_NODES] = N_EDGES;

    if (cnt <= CAP_B) {
        for (int p = t; p < cnt; p += 256) {
            const unsigned v = binned[rbase + p];
            const int dl  = v & (BIN_NODES - 1);
            const int rel = lofs[dl] + atomicAdd(&lcur[dl], 1);
            sseg[rel] = (int)(v >> BIN_SHIFT);
        }
        __syncthreads();
        for (int p = t; p < cnt; p += 256)
            slot[rbase + p] = sseg[p];
    } else {
        // statistically unreachable fallback (correct, uncoalesced)
        for (int p = t; p < cnt; p += 256) {
            const unsigned v = binned[rbase + p];
            const int dl  = v & (BIN_NODES - 1);
            const int rel = lofs[dl] + atomicAdd(&lcur[dl], 1);
            slot[rbase + rel] = (int)(v >> BIN_SHIFT);
        }
    }
}

// ---------------------------------------------------------------------------
// gather_h: wave per node. bf16 rows (128 B = ONE cache line per edge).
// ---------------------------------------------------------------------------
__global__ __launch_bounds__(256) void gather_h(
    const float*  __restrict__ x,
    const unsigned char* __restrict__ rx,
    const int*    __restrict__ off,
    const int*    __restrict__ slot,
    unsigned*     __restrict__ hbuf)
{
    const int wid  = (blockIdx.x * blockDim.x + threadIdx.x) >> 6;
    const int lane = threadIdx.x & 63;
    if (wid >= N_NODES) return;

    const int beg = off[wid];
    const int deg = off[wid + 1] - beg;

    const int gsub      = lane & 7;
    const int chunkByte = (lane >> 3) * 16;

    const float xself = x[(size_t)wid * DIM + lane];

    float acc[8];
    #pragma unroll
    for (int e = 0; e < 8; ++e) acc[e] = 0.f;

    for (int kb = 0; kb < deg; kb += 64) {
        const int nv = min(64, deg - kb);
        const int my = (kb + lane < deg) ? slot[beg + kb + lane] : 0;

        uint4 buf[8];
        #pragma unroll
        for (int j = 0; j < 8; ++j) {
            if (j * 8 < nv) {
                const int s = __shfl(my, j * 8 + gsub, 64);
                buf[j] = *reinterpret_cast<const uint4*>(
                    rx + (size_t)s * 128 + chunkByte);
            }
        }
        #pragma unroll
        for (int j = 0; j < 8; ++j) {
            if (j * 8 < nv) {
                if (j * 8 + gsub < nv) {
                    acc[0] += bflo(buf[j].x); acc[1] += bfhi(buf[j].x);
                    acc[2] += bflo(buf[j].y); acc[3] += bfhi(buf[j].y);
                    acc[4] += bflo(buf[j].z); acc[5] += bfhi(buf[j].z);
                    acc[6] += bflo(buf[j].w); acc[7] += bfhi(buf[j].w);
                }
            }
        }
    }

    #pragma unroll
    for (int m = 1; m < 8; m <<= 1) {
        #pragma unroll
        for (int e = 0; e < 8; ++e) acc[e] += __shfl_xor(acc[e], m, 64);
    }

    const float s0 = (gsub & 1) ? acc[1] : acc[0];
    const float s1 = (gsub & 1) ? acc[3] : acc[2];
    const float s2 = (gsub & 1) ? acc[5] : acc[4];
    const float s3 = (gsub & 1) ? acc[7] : acc[6];
    const float t0 = (gsub & 2) ? s1 : s0;
    const float t1 = (gsub & 2) ? s3 : s2;
    const float agg = (gsub & 4) ? t1 : t0;

    const float h = xself + agg;

    const float hnext = __shfl_down(h, 1, 64);
    if (!(lane & 1)) {
        hbuf[((size_t)wid * DIM + lane) >> 1] = f2bf(h) | (f2bf(hnext) << 16);
    }
}

// ---------------------------------------------------------------------------
// mlp8: one wave processes 8 nodes -> each W column load reused 8x.
// ---------------------------------------------------------------------------
__device__ __forceinline__ float lanebcast(float v, int i) {
    return __uint_as_float(__builtin_amdgcn_readlane(__float_as_uint(v), i));
}

__global__ __launch_bounds__(256) void mlp8(
    const unsigned short* __restrict__ hbuf,
    const float* __restrict__ W1, const float* __restrict__ b1,
    const float* __restrict__ W2, const float* __restrict__ b2,
    float* __restrict__ out)
{
    const int wv   = (blockIdx.x * blockDim.x + threadIdx.x) >> 6;
    const int lane = threadIdx.x & 63;
    const int n0   = wv * 8;
    if (n0 >= N_NODES) return;

    float h[8];
    #pragma unroll
    for (int b = 0; b < 8; ++b) {
        const int n = n0 + b;
        h[b] = (n < N_NODES)
             ? __uint_as_float((unsigned)hbuf[(size_t)n * DIM + lane] << 16)
             : 0.f;
    }

    float acc[8];
    #pragma unroll
    for (int b = 0; b < 8; ++b) acc[b] = b1[lane];
    #pragma unroll
    for (int i = 0; i < DIM; ++i) {
        const float w = W1[i * DIM + lane];
        #pragma unroll
        for (int b = 0; b < 8; ++b)
            acc[b] = fmaf(lanebcast(h[b], i), w, acc[b]);
    }
    float y[8];
    #pragma unroll
    for (int b = 0; b < 8; ++b) y[b] = fmaxf(acc[b], 0.f);

    float acc2[8];
    #pragma unroll
    for (int b = 0; b < 8; ++b) acc2[b] = b2[lane];
    #pragma unroll
    for (int i = 0; i < DIM; ++i) {
        const float w = W2[i * DIM + lane];
        #pragma unroll
        for (int b = 0; b < 8; ++b)
            acc2[b] = fmaf(lanebcast(y[b], i), w, acc2[b]);
    }

    #pragma unroll
    for (int b = 0; b < 8; ++b) {
        const int n = n0 + b;
        if (n < N_NODES)
            out[(size_t)n * DIM + lane] = fmaxf(acc2[b], 0.f);
    }
}

// ---------------------------------------------------------------------------
extern "C" void kernel_launch(void* const* d_in, const int* in_sizes, int n_in,
                              void* d_out, int out_size, void* d_ws, size_t ws_size,
                              hipStream_t stream) {
    const float* x  = (const float*)d_in[0];
    const int*   ei = (const int*)d_in[1];
    const float* W1 = (const float*)d_in[2];
    const float* b1 = (const float*)d_in[3];
    const float* W2 = (const float*)d_in[4];
    const float* b2 = (const float*)d_in[5];
    float* out = (float*)d_out;

    // rx (relu(x) in bf16, 12.8 MB) lives in d_out; fully consumed by gather_h
    // before mlp8 overwrites d_out.
    unsigned* rx = (unsigned*)d_out;

    // workspace (ints): off | binc | binbase | gcur | slot | hbuf
    // binned aliases hbuf (binned dead before gather_h writes hbuf).
    int* off     = (int*)d_ws;         // N_NODES + 1 (padded to 100352)
    int* binc    = off + 100352;       // 256
    int* binbase = binc + 256;         // NBINS + 1 (padded to 256)
    int* gcur    = binbase + 256;      // 256
    int* slot    = gcur + 256;         // N_EDGES
    unsigned* hbuf   = (unsigned*)(slot + N_EDGES);  // N_NODES*DIM bf16
    unsigned* binned = hbuf;                         // N_EDGES uints (alias)

    hipMemsetAsync(binc, 0, NBINS * sizeof(int), stream);

    prep_relu<<<(N_NODES * DIM / 4 + 255) / 256, 256, 0, stream>>>(x, rx);

    const int eblocks4 = (N_EDGES / 4 + 255) / 256;
    bincount<<<eblocks4, 256, 0, stream>>>(ei, binc);
    binscan<<<1, 256, 0, stream>>>(binc, binbase, gcur);
    binscatter<<<NBLK_A, 256, 0, stream>>>(ei, gcur, binned);
    binsort<<<NBINS, 256, 0, stream>>>(binned, binbase, off, slot);

    gather_h<<<(N_NODES + 3) / 4, 256, 0, stream>>>(
        x, (const unsigned char*)rx, off, slot, hbuf);

    mlp8<<<(N_NODES / 8 + 3) / 4, 256, 0, stream>>>(
        (const unsigned short*)hbuf, W1, b1, W2, b2, out);
}

// Round 9
// 145.393 us; speedup vs baseline: 10.3745x; 1.2564x over previous
//
#include <hip/hip_runtime.h>

#define N_NODES 100000
#define N_EDGES 1600000
#define DIM 64

#define BIN_SHIFT 9
#define BIN_NODES 512
#define NBINS ((N_NODES + BIN_NODES - 1) / BIN_NODES)   // 196
#define TILE_A 4096
#define NBLK_A ((N_EDGES + TILE_A - 1) / TILE_A)        // 391
#define CAP_B 9216          // mean 8192 + ~11 sigma

typedef __attribute__((ext_vector_type(8))) short bf16x8;
typedef __attribute__((ext_vector_type(4))) float f32x4;

// ---- bf16 helpers (hand-rolled, RNE; inputs are finite) --------------------
__device__ __forceinline__ float bflo(unsigned u) { return __uint_as_float(u << 16); }
__device__ __forceinline__ float bfhi(unsigned u) { return __uint_as_float(u & 0xFFFF0000u); }
__device__ __forceinline__ unsigned f2bf(float f) {
    unsigned u = __float_as_uint(f);
    u += 0x7FFFu + ((u >> 16) & 1u);
    return u >> 16;
}

// ---------------------------------------------------------------------------
// prep: rx = relu(x) as bf16, packed. 4 floats / thread.
// ---------------------------------------------------------------------------
__global__ __launch_bounds__(256) void prep_relu(
    const float* __restrict__ x, unsigned* __restrict__ rx)
{
    const int i = blockIdx.x * blockDim.x + threadIdx.x;
    if (i >= N_NODES * DIM / 4) return;
    const float4 v = reinterpret_cast<const float4*>(x)[i];
    uint2 o;
    o.x = f2bf(fmaxf(v.x, 0.f)) | (f2bf(fmaxf(v.y, 0.f)) << 16);
    o.y = f2bf(fmaxf(v.z, 0.f)) | (f2bf(fmaxf(v.w, 0.f)) << 16);
    reinterpret_cast<uint2*>(rx)[i] = o;
}

// ---------------------------------------------------------------------------
// wprep: prepack W1,W2 into MFMA B-frag lane order, bf16.
// short index = (((L*4+n)*2+kk)*64 + lane)*8 + j
//   value = W_L[kk*32 + (lane>>4)*8 + j][n*16 + (lane&15)]
// ---------------------------------------------------------------------------
__global__ __launch_bounds__(256) void wprep(
    const float* __restrict__ W1, const float* __restrict__ W2,
    unsigned short* __restrict__ Wpk)
{
    const int idx = blockIdx.x * 256 + threadIdx.x;
    if (idx >= 8192) return;
    const int j    = idx & 7;
    const int lane = (idx >> 3) & 63;
    const int kk   = (idx >> 9) & 1;
    const int n    = (idx >> 10) & 3;
    const int L    = idx >> 12;
    const float* W = L ? W2 : W1;
    const int k    = kk * 32 + (lane >> 4) * 8 + j;
    const int col  = n * 16 + (lane & 15);
    Wpk[idx] = (unsigned short)f2bf(W[k * DIM + col]);
}

// ---------------------------------------------------------------------------
// bincount: coarse-bin histogram via LDS aggregation.
// ---------------------------------------------------------------------------
__global__ __launch_bounds__(256) void bincount(
    const int* __restrict__ ei, int* __restrict__ binc)
{
    __shared__ int lh[NBINS];
    for (int i = threadIdx.x; i < NBINS; i += 256) lh[i] = 0;
    __syncthreads();
    const int t = blockIdx.x * blockDim.x + threadIdx.x;
    const int e = t * 4;
    if (e + 3 < N_EDGES) {
        const int4 d4 = *reinterpret_cast<const int4*>(ei + N_EDGES + e);
        atomicAdd(&lh[d4.x >> BIN_SHIFT], 1);
        atomicAdd(&lh[d4.y >> BIN_SHIFT], 1);
        atomicAdd(&lh[d4.z >> BIN_SHIFT], 1);
        atomicAdd(&lh[d4.w >> BIN_SHIFT], 1);
    } else {
        for (int k = e; k < N_EDGES; ++k)
            atomicAdd(&lh[ei[N_EDGES + k] >> BIN_SHIFT], 1);
    }
    __syncthreads();
    for (int i = threadIdx.x; i < NBINS; i += 256)
        if (lh[i]) atomicAdd(&binc[i], lh[i]);
}

// ---------------------------------------------------------------------------
// binscan: single block scans the 196 bin counts -> binbase; seeds gcur.
// ---------------------------------------------------------------------------
__global__ __launch_bounds__(256) void binscan(
    const int* __restrict__ binc, int* __restrict__ binbase,
    int* __restrict__ gcur)
{
    __shared__ int s[256];
    const int t = threadIdx.x;
    const int v = (t < NBINS) ? binc[t] : 0;
    s[t] = v;
    __syncthreads();
    #pragma unroll
    for (int d = 1; d < 256; d <<= 1) {
        const int add = (t >= d) ? s[t - d] : 0;
        __syncthreads();
        s[t] += add;
        __syncthreads();
    }
    if (t < NBINS) {
        const int base = s[t] - v;
        binbase[t] = base;
        gcur[t]    = base;
    }
    if (t == 0) binbase[NBINS] = N_EDGES;
}

// ---------------------------------------------------------------------------
// Pass A: binscatter (unchanged).
// ---------------------------------------------------------------------------
__global__ __launch_bounds__(256) void binscatter(
    const int* __restrict__ ei,
    int* __restrict__ gcur,
    unsigned* __restrict__ binned)
{
    __shared__ int lhist[NBINS];
    __shared__ int lbase[NBINS];
    __shared__ int lcur[NBINS];
    __shared__ int ldelta[NBINS];
    __shared__ int ls[256];
    __shared__ unsigned staged[TILE_A];
    __shared__ unsigned char sbin[TILE_A];

    const int t  = threadIdx.x;
    const int e0 = blockIdx.x * TILE_A;
    const int n  = min(TILE_A, N_EDGES - e0);

    for (int i = t; i < NBINS; i += 256) { lhist[i] = 0; lcur[i] = 0; }
    __syncthreads();

    int      mybin[TILE_A / 256];
    unsigned myval[TILE_A / 256];
    #pragma unroll
    for (int j = 0; j < TILE_A / 256; ++j) {
        const int idx = t + j * 256;
        if (idx < n) {
            const int s = ei[e0 + idx];
            const int d = ei[N_EDGES + e0 + idx];
            mybin[j] = d >> BIN_SHIFT;
            myval[j] = ((unsigned)s << BIN_SHIFT) | (unsigned)(d & (BIN_NODES - 1));
            atomicAdd(&lhist[mybin[j]], 1);
        } else {
            mybin[j] = -1;
        }
    }
    __syncthreads();

    ls[t] = (t < NBINS) ? lhist[t] : 0;
    __syncthreads();
    #pragma unroll
    for (int d = 1; d < 256; d <<= 1) {
        const int add = (t >= d) ? ls[t - d] : 0;
        __syncthreads();
        ls[t] += add;
        __syncthreads();
    }
    if (t < NBINS) lbase[t] = ls[t] - lhist[t];
    __syncthreads();

    if (t < NBINS) {
        const int c = lhist[t];
        ldelta[t] = (c > 0) ? (atomicAdd(&gcur[t], c) - lbase[t]) : 0;
    }
    __syncthreads();

    #pragma unroll
    for (int j = 0; j < TILE_A / 256; ++j) {
        if (mybin[j] >= 0) {
            const int p = lbase[mybin[j]] + atomicAdd(&lcur[mybin[j]], 1);
            staged[p] = myval[j];
            sbin[p]   = (unsigned char)mybin[j];
        }
    }
    __syncthreads();

    for (int p = t; p < n; p += 256)
        binned[p + ldelta[sbin[p]]] = staged[p];
}

// ---------------------------------------------------------------------------
// Pass B: binsort (unchanged).
// ---------------------------------------------------------------------------
__global__ __launch_bounds__(256) void binsort(
    const unsigned* __restrict__ binned,
    const int* __restrict__ binbase,
    int* __restrict__ off,
    int* __restrict__ slot)
{
    __shared__ int lhist[BIN_NODES];
    __shared__ int lofs[BIN_NODES];
    __shared__ int lcur[BIN_NODES];
    __shared__ int ls[256];
    __shared__ int sseg[CAP_B];

    const int b     = blockIdx.x;
    const int node0 = b << BIN_SHIFT;
    const int nloc  = min(BIN_NODES, N_NODES - node0);
    const int rbase = binbase[b];
    const int cnt   = binbase[b + 1] - rbase;
    const int t     = threadIdx.x;

    for (int i = t; i < BIN_NODES; i += 256) { lhist[i] = 0; lcur[i] = 0; }
    __syncthreads();

    for (int p = t; p < cnt; p += 256)
        atomicAdd(&lhist[binned[rbase + p] & (BIN_NODES - 1)], 1);
    __syncthreads();

    const int a0 = lhist[2 * t];
    const int a1 = lhist[2 * t + 1];
    const int ps = a0 + a1;
    ls[t] = ps;
    __syncthreads();
    #pragma unroll
    for (int d = 1; d < 256; d <<= 1) {
        const int add = (t >= d) ? ls[t - d] : 0;
        __syncthreads();
        ls[t] += add;
        __syncthreads();
    }
    const int pbase = ls[t] - ps;
    lofs[2 * t]     = pbase;
    lofs[2 * t + 1] = pbase + a0;
    __syncthreads();

    for (int i = t; i < nloc; i += 256)
        off[node0 + i] = rbase + lofs[i];
    if (b == NBINS - 1 && t == 0) off[N_NODES] = N_EDGES;

    if (cnt <= CAP_B) {
        for (int p = t; p < cnt; p += 256) {
            const unsigned v = binned[rbase + p];
            const int dl  = v & (BIN_NODES - 1);
            const int rel = lofs[dl] + atomicAdd(&lcur[dl], 1);
            sseg[rel] = (int)(v >> BIN_SHIFT);
        }
        __syncthreads();
        for (int p = t; p < cnt; p += 256)
            slot[rbase + p] = sseg[p];
    } else {
        for (int p = t; p < cnt; p += 256) {
            const unsigned v = binned[rbase + p];
            const int dl  = v & (BIN_NODES - 1);
            const int rel = lofs[dl] + atomicAdd(&lcur[dl], 1);
            slot[rbase + rel] = (int)(v >> BIN_SHIFT);
        }
    }
}

// ---------------------------------------------------------------------------
// gather_h: wave per node (unchanged).
// ---------------------------------------------------------------------------
__global__ __launch_bounds__(256) void gather_h(
    const float*  __restrict__ x,
    const unsigned char* __restrict__ rx,
    const int*    __restrict__ off,
    const int*    __restrict__ slot,
    unsigned*     __restrict__ hbuf)
{
    const int wid  = (blockIdx.x * blockDim.x + threadIdx.x) >> 6;
    const int lane = threadIdx.x & 63;
    if (wid >= N_NODES) return;

    const int beg = off[wid];
    const int deg = off[wid + 1] - beg;

    const int gsub      = lane & 7;
    const int chunkByte = (lane >> 3) * 16;

    const float xself = x[(size_t)wid * DIM + lane];

    float acc[8];
    #pragma unroll
    for (int e = 0; e < 8; ++e) acc[e] = 0.f;

    for (int kb = 0; kb < deg; kb += 64) {
        const int nv = min(64, deg - kb);
        const int my = (kb + lane < deg) ? slot[beg + kb + lane] : 0;

        uint4 buf[8];
        #pragma unroll
        for (int j = 0; j < 8; ++j) {
            if (j * 8 < nv) {
                const int s = __shfl(my, j * 8 + gsub, 64);
                buf[j] = *reinterpret_cast<const uint4*>(
                    rx + (size_t)s * 128 + chunkByte);
            }
        }
        #pragma unroll
        for (int j = 0; j < 8; ++j) {
            if (j * 8 < nv) {
                if (j * 8 + gsub < nv) {
                    acc[0] += bflo(buf[j].x); acc[1] += bfhi(buf[j].x);
                    acc[2] += bflo(buf[j].y); acc[3] += bfhi(buf[j].y);
                    acc[4] += bflo(buf[j].z); acc[5] += bfhi(buf[j].z);
                    acc[6] += bflo(buf[j].w); acc[7] += bfhi(buf[j].w);
                }
            }
        }
    }

    #pragma unroll
    for (int m = 1; m < 8; m <<= 1) {
        #pragma unroll
        for (int e = 0; e < 8; ++e) acc[e] += __shfl_xor(acc[e], m, 64);
    }

    const float s0 = (gsub & 1) ? acc[1] : acc[0];
    const float s1 = (gsub & 1) ? acc[3] : acc[2];
    const float s2 = (gsub & 1) ? acc[5] : acc[4];
    const float s3 = (gsub & 1) ? acc[7] : acc[6];
    const float t0 = (gsub & 2) ? s1 : s0;
    const float t1 = (gsub & 2) ? s3 : s2;
    const float agg = (gsub & 4) ? t1 : t0;

    const float h = xself + agg;

    const float hnext = __shfl_down(h, 1, 64);
    if (!(lane & 1)) {
        hbuf[((size_t)wid * DIM + lane) >> 1] = f2bf(h) | (f2bf(hnext) << 16);
    }
}

// ---------------------------------------------------------------------------
// mlp_mfma: per wave, 16 nodes. Two back-to-back MFMA GEMMs with fused bias
// (in the accumulator init) + relu. Y transposes through a per-wave LDS tile
// (f32, row stride 68 words -> <=2-way banks on both write and b128 read).
// ---------------------------------------------------------------------------
__global__ __launch_bounds__(256) void mlp_mfma(
    const unsigned* __restrict__ hbuf,       // bf16 rows, 128 B each
    const unsigned short* __restrict__ Wpk,  // prepacked B-frags
    const float* __restrict__ b1,
    const float* __restrict__ b2,
    float* __restrict__ out)
{
    __shared__ float yt[4][16 * 68];

    const int wiv  = threadIdx.x >> 6;
    const int lane = threadIdx.x & 63;
    const int wid  = blockIdx.x * 4 + wiv;
    const int r0   = wid * 16;
    if (r0 >= N_NODES) return;

    const int lrow = lane & 15;
    const int lgrp = lane >> 4;

    // A-frags for layer 1, straight from hbuf (row = r0+lrow, clamped tail)
    const int hrow = min(r0 + lrow, N_NODES - 1);
    const uint4* hrowp =
        reinterpret_cast<const uint4*>((const char*)hbuf + (size_t)hrow * 128);
    union UF { uint4 u; bf16x8 v; };
    UF ha0, ha1;
    ha0.u = hrowp[lgrp];        // k = 0..31 slice
    ha1.u = hrowp[lgrp + 4];    // k = 32..63 slice

    const uint4* wp = reinterpret_cast<const uint4*>(Wpk);

    // ---- layer 1: acc = H @ W1 + b1, relu -> LDS
    float* my = &yt[wiv][0];
    #pragma unroll
    for (int n = 0; n < 4; ++n) {
        const float bi = b1[n * 16 + lrow];
        f32x4 acc = {bi, bi, bi, bi};
        UF bw0, bw1;
        bw0.u = wp[(n * 2 + 0) * 64 + lane];
        bw1.u = wp[(n * 2 + 1) * 64 + lane];
        acc = __builtin_amdgcn_mfma_f32_16x16x32_bf16(ha0.v, bw0.v, acc, 0, 0, 0);
        acc = __builtin_amdgcn_mfma_f32_16x16x32_bf16(ha1.v, bw1.v, acc, 0, 0, 0);
        #pragma unroll
        for (int i = 0; i < 4; ++i)
            my[(lgrp * 4 + i) * 68 + n * 16 + lrow] = fmaxf(acc[i], 0.f);
    }
    // per-wave private LDS region: same wave reads below; compiler inserts
    // the lgkmcnt waits for the dependency — no barrier needed.

    // ---- re-enter A-layout: lane needs Y[lrow][kk*32 + lgrp*8 + j]
    const float* yr = &yt[wiv][lrow * 68 + lgrp * 8];
    const float4 p0 = *reinterpret_cast<const float4*>(yr + 0);
    const float4 p1 = *reinterpret_cast<const float4*>(yr + 4);
    const float4 p2 = *reinterpret_cast<const float4*>(yr + 32);
    const float4 p3 = *reinterpret_cast<const float4*>(yr + 36);

    union UB { bf16x8 v; unsigned short s[8]; };
    UB ya0, ya1;
    ya0.s[0] = (unsigned short)f2bf(p0.x); ya0.s[1] = (unsigned short)f2bf(p0.y);
    ya0.s[2] = (unsigned short)f2bf(p0.z); ya0.s[3] = (unsigned short)f2bf(p0.w);
    ya0.s[4] = (unsigned short)f2bf(p1.x); ya0.s[5] = (unsigned short)f2bf(p1.y);
    ya0.s[6] = (unsigned short)f2bf(p1.z); ya0.s[7] = (unsigned short)f2bf(p1.w);
    ya1.s[0] = (unsigned short)f2bf(p2.x); ya1.s[1] = (unsigned short)f2bf(p2.y);
    ya1.s[2] = (unsigned short)f2bf(p2.z); ya1.s[3] = (unsigned short)f2bf(p2.w);
    ya1.s[4] = (unsigned short)f2bf(p3.x); ya1.s[5] = (unsigned short)f2bf(p3.y);
    ya1.s[6] = (unsigned short)f2bf(p3.z); ya1.s[7] = (unsigned short)f2bf(p3.w);

    // ---- layer 2: out = relu(Y @ W2 + b2)
    #pragma unroll
    for (int n = 0; n < 4; ++n) {
        const float bi = b2[n * 16 + lrow];
        f32x4 acc = {bi, bi, bi, bi};
        UF bw0, bw1;
        bw0.u = wp[(8 + n * 2 + 0) * 64 + lane];
        bw1.u = wp[(8 + n * 2 + 1) * 64 + lane];
        acc = __builtin_amdgcn_mfma_f32_16x16x32_bf16(ya0.v, bw0.v, acc, 0, 0, 0);
        acc = __builtin_amdgcn_mfma_f32_16x16x32_bf16(ya1.v, bw1.v, acc, 0, 0, 0);
        #pragma unroll
        for (int i = 0; i < 4; ++i) {
            const int r = r0 + lgrp * 4 + i;
            if (r < N_NODES)
                out[(size_t)r * DIM + n * 16 + lrow] = fmaxf(acc[i], 0.f);
        }
    }
}

// ---------------------------------------------------------------------------
extern "C" void kernel_launch(void* const* d_in, const int* in_sizes, int n_in,
                              void* d_out, int out_size, void* d_ws, size_t ws_size,
                              hipStream_t stream) {
    const float* x  = (const float*)d_in[0];
    const int*   ei = (const int*)d_in[1];
    const float* W1 = (const float*)d_in[2];
    const float* b1 = (const float*)d_in[3];
    const float* W2 = (const float*)d_in[4];
    const float* b2 = (const float*)d_in[5];
    float* out = (float*)d_out;

    // rx (relu(x) in bf16, 12.8 MB) lives in d_out; fully consumed by gather_h
    // before mlp_mfma overwrites d_out.
    unsigned* rx = (unsigned*)d_out;

    // workspace (ints): off | binc | binbase | gcur | slot | hbuf | Wpk
    // binned aliases hbuf (binned dead before gather_h writes hbuf).
    int* off     = (int*)d_ws;         // N_NODES + 1 (padded to 100352)
    int* binc    = off + 100352;       // 256
    int* binbase = binc + 256;         // NBINS + 1 (padded to 256)
    int* gcur    = binbase + 256;      // 256
    int* slot    = gcur + 256;         // N_EDGES
    unsigned* hbuf   = (unsigned*)(slot + N_EDGES);   // N_NODES*DIM bf16
    unsigned* binned = hbuf;                          // N_EDGES uints (alias)
    unsigned short* Wpk =
        (unsigned short*)(hbuf + (size_t)N_NODES * DIM / 2);  // 8192 bf16

    hipMemsetAsync(binc, 0, NBINS * sizeof(int), stream);

    prep_relu<<<(N_NODES * DIM / 4 + 255) / 256, 256, 0, stream>>>(x, rx);
    wprep<<<32, 256, 0, stream>>>(W1, W2, Wpk);

    const int eblocks4 = (N_EDGES / 4 + 255) / 256;
    bincount<<<eblocks4, 256, 0, stream>>>(ei, binc);
    binscan<<<1, 256, 0, stream>>>(binc, binbase, gcur);
    binscatter<<<NBLK_A, 256, 0, stream>>>(ei, gcur, binned);
    binsort<<<NBINS, 256, 0, stream>>>(binned, binbase, off, slot);

    gather_h<<<(N_NODES + 3) / 4, 256, 0, stream>>>(
        x, (const unsigned char*)rx, off, slot, hbuf);

    mlp_mfma<<<(N_NODES + 63) / 64, 256, 0, stream>>>(
        hbuf, Wpk, b1, b2, out);
}